// Round 7
// baseline (467.018 us; speedup 1.0000x reference)
//
#include <hip/hip_runtime.h>

#define NB 8
#define NN 2048
#define NF 256

typedef __attribute__((ext_vector_type(8))) short bf16x8;
typedef __attribute__((ext_vector_type(4))) float f32x4;

__device__ __forceinline__ unsigned short f2bf(float x) {
  union { float f; unsigned int i; } c; c.f = x;
  unsigned int r = c.i + 0x7FFFu + ((c.i >> 16) & 1u);
  return (unsigned short)(r >> 16);
}
// round-half-up bf16 (1 add + 1 shift) — hot convert paths
__device__ __forceinline__ unsigned short f2bf_fast(float x) {
  union { float f; unsigned int i; } c; c.f = x;
  return (unsigned short)((c.i + 0x8000u) >> 16);
}
__device__ __forceinline__ bf16x8 cvt8(float4 c0, float4 c1) {
  union { bf16x8 v8; unsigned short us[8]; } cu;
  cu.us[0] = f2bf_fast(c0.x); cu.us[1] = f2bf_fast(c0.y);
  cu.us[2] = f2bf_fast(c0.z); cu.us[3] = f2bf_fast(c0.w);
  cu.us[4] = f2bf_fast(c1.x); cu.us[5] = f2bf_fast(c1.y);
  cu.us[6] = f2bf_fast(c1.z); cu.us[7] = f2bf_fast(c1.w);
  return cu.v8;
}

// ---------------------------------------------------------------------------
// k_prep: WT[f][k] = bf16(W[k][f]);  u = W @ a1, v = W @ a2  (fp32)
// ---------------------------------------------------------------------------
__global__ __launch_bounds__(256) void k_prep(
    const float* __restrict__ W, const float* __restrict__ a,
    unsigned short* __restrict__ WT, float* __restrict__ u, float* __restrict__ v) {
  int t = threadIdx.x;
  if (blockIdx.x < 256) {
    int k = blockIdx.x;
    WT[t * 256 + k] = f2bf(W[k * 256 + t]);
  } else {
    float su = 0.f, sv = 0.f;
    for (int o = 0; o < 256; ++o) {
      float w = W[t * 256 + o];
      su += w * a[o];
      sv += w * a[256 + o];
    }
    u[t] = su; v[t] = sv;
  }
}

// ---------------------------------------------------------------------------
// k_whtp: fused Wh^T + proj. Block = 16i x 256f, grid 1024 (8b x 128 tiles).
// Stage: h tile fp32 -> bf16 XOR-swizzled LDS (h read ONCE), fp32 proj dots
//        (Wh1/Wh2) via 16-lane shuffle reduce.
// GEMM:  4 waves split f (64f each); A = WTr global (L2-hot) 16B frags,
//        B = LDS h rows ds_read_b128 (2-way conflict = free).
// ---------------------------------------------------------------------------
__global__ __launch_bounds__(256) void k_whtp(
    const float* __restrict__ h, const unsigned short* __restrict__ WTr,
    const float* __restrict__ u, const float* __restrict__ v,
    unsigned short* __restrict__ WhT, float* __restrict__ Wh1,
    float* __restrict__ Wh2) {
  __shared__ unsigned short hs[16 * 256];  // 8 KB
  __shared__ float us[256], vs[256];
  int bx = blockIdx.x;
  int b = bx >> 7;
  int i0 = (bx & 127) * 16;
  int t = threadIdx.x;

  us[t] = u[t]; vs[t] = v[t];

  // ---- staging + proj: thread t -> row ir = t>>4, k-slice kg = (t&15)*16 ---
  int ir = t >> 4, kg = (t & 15) * 16;
  const float* hrow = h + ((size_t)(b * NN + i0 + ir)) * NF + kg;
  float4 c0 = *(const float4*)(hrow);
  float4 c1 = *(const float4*)(hrow + 4);
  float4 c2 = *(const float4*)(hrow + 8);
  float4 c3 = *(const float4*)(hrow + 12);
  __syncthreads();  // us/vs ready

  float su, sv;
  {
    const float* up = us + kg; const float* vp = vs + kg;
    su = c0.x*up[0] + c0.y*up[1] + c0.z*up[2] + c0.w*up[3]
       + c1.x*up[4] + c1.y*up[5] + c1.z*up[6] + c1.w*up[7]
       + c2.x*up[8] + c2.y*up[9] + c2.z*up[10] + c2.w*up[11]
       + c3.x*up[12] + c3.y*up[13] + c3.z*up[14] + c3.w*up[15];
    sv = c0.x*vp[0] + c0.y*vp[1] + c0.z*vp[2] + c0.w*vp[3]
       + c1.x*vp[4] + c1.y*vp[5] + c1.z*vp[6] + c1.w*vp[7]
       + c2.x*vp[8] + c2.y*vp[9] + c2.z*vp[10] + c2.w*vp[11]
       + c3.x*vp[12] + c3.y*vp[13] + c3.z*vp[14] + c3.w*vp[15];
  }
#pragma unroll
  for (int off = 8; off >= 1; off >>= 1) {
    su += __shfl_xor(su, off);
    sv += __shfl_xor(sv, off);
  }
  if ((t & 15) == 0) {
    Wh1[b * NN + i0 + ir] = su;
    Wh2[b * NN + i0 + ir] = sv;
  }

  // swizzled bf16 store: element k -> ((k&~7) ^ (ir*8)) + (k&7)
  int swz = ir * 8;
  unsigned short* srow = hs + ir * 256;
  {
    union { short4 v4; unsigned short us4[4]; } pk;
    float4 cc[4] = {c0, c1, c2, c3};
#pragma unroll
    for (int q = 0; q < 4; ++q) {
      int basek = kg + q * 4;
      int pos = ((basek & ~7) ^ swz) + (basek & 7);
      pk.us4[0] = f2bf_fast(cc[q].x); pk.us4[1] = f2bf_fast(cc[q].y);
      pk.us4[2] = f2bf_fast(cc[q].z); pk.us4[3] = f2bf_fast(cc[q].w);
      *(short4*)(srow + pos) = pk.v4;
    }
  }
  __syncthreads();

  // ---- GEMM: D[f][i] = sum_k WT[f][k] * h[i][k] ---------------------------
  int wave = t >> 6, lane = t & 63;
  int l15 = lane & 15, q8 = (lane >> 4) * 8;
  int fW = wave * 64;
  const unsigned short* bRow = hs + l15 * 256;
  int swzB = l15 * 8;

  f32x4 acc[4];
#pragma unroll
  for (int ft = 0; ft < 4; ++ft) acc[ft] = (f32x4){0.f, 0.f, 0.f, 0.f};

#pragma unroll
  for (int kk = 0; kk < NF; kk += 32) {
    bf16x8 bfr = *(const bf16x8*)(bRow + ((kk + q8) ^ swzB));
    bf16x8 af[4];
#pragma unroll
    for (int ft = 0; ft < 4; ++ft) {
      int f = fW + ft * 16 + l15;
      af[ft] = *(const bf16x8*)(WTr + f * 256 + kk + q8);
    }
#pragma unroll
    for (int ft = 0; ft < 4; ++ft)
      acc[ft] = __builtin_amdgcn_mfma_f32_16x16x32_bf16(af[ft], bfr, acc[ft], 0, 0, 0);
  }

  unsigned short* WhTb = WhT + (size_t)b * NF * NN;
  int q4 = (lane >> 4) * 4;
#pragma unroll
  for (int ft = 0; ft < 4; ++ft)
#pragma unroll
    for (int r = 0; r < 4; ++r) {
      int f = fW + ft * 16 + q4 + r;
      int i = i0 + l15;
      WhTb[(size_t)f * NN + i] = f2bf(acc[ft][r]);
    }
}

// ---------------------------------------------------------------------------
// k_attn: WAVE per row (no barriers, no LDS). 4 rows / 256-thr block.
// lane handles 32 j's: chunks c=0..7, j = c*256 + lane*4 (coalesced)
// launch_bounds(256,6): cap VGPR for ~24 waves/CU -> more loads in flight
// ---------------------------------------------------------------------------
__global__ __launch_bounds__(256, 6) void k_attn(
    const int* __restrict__ adj, const float* __restrict__ Wh1,
    const float* __restrict__ Wh2, float* __restrict__ att) {
  const float NEGBIG = -9.0e15f;
  int wave = threadIdx.x >> 6, lane = threadIdx.x & 63;
  int row = blockIdx.x * 4 + wave;
  int b = row >> 11;
  const int* arow = adj + (size_t)row * NN;
  const float* w2 = Wh2 + ((size_t)b << 11);
  float w1 = Wh1[row];

  float s[32];
#pragma unroll
  for (int c = 0; c < 8; ++c) {
    int j = c * 256 + lane * 4;
    int4 av = *(const int4*)(arow + j);
    float4 pv = *(const float4*)(w2 + j);
    float x;
    x = w1 + pv.x; x = x >= 0.f ? x : 0.2f * x; s[c*4+0] = (av.x > 0) ? x : NEGBIG;
    x = w1 + pv.y; x = x >= 0.f ? x : 0.2f * x; s[c*4+1] = (av.y > 0) ? x : NEGBIG;
    x = w1 + pv.z; x = x >= 0.f ? x : 0.2f * x; s[c*4+2] = (av.z > 0) ? x : NEGBIG;
    x = w1 + pv.w; x = x >= 0.f ? x : 0.2f * x; s[c*4+3] = (av.w > 0) ? x : NEGBIG;
  }

  float m = s[0];
#pragma unroll
  for (int k = 1; k < 32; ++k) m = fmaxf(m, s[k]);
#pragma unroll
  for (int off = 32; off >= 1; off >>= 1) m = fmaxf(m, __shfl_xor(m, off));

  float sum = 0.f;
#pragma unroll
  for (int k = 0; k < 32; ++k) { s[k] = __expf(s[k] - m); sum += s[k]; }
#pragma unroll
  for (int off = 32; off >= 1; off >>= 1) sum += __shfl_xor(sum, off);
  float inv = 1.0f / sum;

  float* orow = att + (size_t)row * NN;
#pragma unroll
  for (int c = 0; c < 8; ++c) {
    int j = c * 256 + lane * 4;
    float4 o = make_float4(s[c*4+0] * inv, s[c*4+1] * inv,
                           s[c*4+2] * inv, s[c*4+3] * inv);
    *(float4*)(orow + j) = o;
  }
}

// ---------------------------------------------------------------------------
// k_out: h_prime = att @ Wh (att fp32 L3-hot -> bf16 in-reg), out = h+elu.
// Block = 16i x 256f, grid 1024 (4 blocks/CU, 16 waves/CU); wave = 16i x 64f.
// K-loop unrolled x2 -> 12 x 16B loads in flight per wave.
// ---------------------------------------------------------------------------
__global__ __launch_bounds__(256, 4) void k_out(
    const float* __restrict__ att, const unsigned short* __restrict__ WhT,
    const float* __restrict__ h, float* __restrict__ out) {
  int bx = blockIdx.x;
  int b = bx >> 7;
  int i0 = (bx & 127) * 16;
  int wave = threadIdx.x >> 6, lane = threadIdx.x & 63;
  int l15 = lane & 15, q8 = (lane >> 4) * 8;
  int fW = wave * 64;
  const float* aRow = att + ((size_t)(b * NN + i0 + l15)) * NN;
  const unsigned short* WTb = WhT + (size_t)b * NF * NN;

  f32x4 acc[4];
#pragma unroll
  for (int nt = 0; nt < 4; ++nt) acc[nt] = (f32x4){0.f, 0.f, 0.f, 0.f};

  for (int kk = 0; kk < NN; kk += 64) {
    const float* p0 = aRow + kk + q8;
    const float* p1 = aRow + kk + 32 + q8;
    float4 a00 = *(const float4*)(p0);
    float4 a01 = *(const float4*)(p0 + 4);
    float4 a10 = *(const float4*)(p1);
    float4 a11 = *(const float4*)(p1 + 4);
    bf16x8 b0[4], b1[4];
#pragma unroll
    for (int nt = 0; nt < 4; ++nt) {
      const unsigned short* q = WTb + (size_t)(fW + nt * 16 + l15) * NN + kk + q8;
      b0[nt] = *(const bf16x8*)(q);
      b1[nt] = *(const bf16x8*)(q + 32);
    }
    bf16x8 a0 = cvt8(a00, a01);
    bf16x8 a1 = cvt8(a10, a11);
#pragma unroll
    for (int nt = 0; nt < 4; ++nt)
      acc[nt] = __builtin_amdgcn_mfma_f32_16x16x32_bf16(a0, b0[nt], acc[nt], 0, 0, 0);
#pragma unroll
    for (int nt = 0; nt < 4; ++nt)
      acc[nt] = __builtin_amdgcn_mfma_f32_16x16x32_bf16(a1, b1[nt], acc[nt], 0, 0, 0);
  }

  int q4 = (lane >> 4) * 4;
#pragma unroll
  for (int nt = 0; nt < 4; ++nt)
#pragma unroll
    for (int r = 0; r < 4; ++r) {
      int i = i0 + q4 + r;
      int f = fW + nt * 16 + l15;
      size_t idx = ((size_t)(b * NN + i)) * NF + f;
      float hp = acc[nt][r];
      float el = hp > 0.f ? hp : expm1f(hp);
      out[idx] = h[idx] + el;
    }
}

// ---------------------------------------------------------------------------
extern "C" void kernel_launch(void* const* d_in, const int* in_sizes, int n_in,
                              void* d_out, int out_size, void* d_ws, size_t ws_size,
                              hipStream_t stream) {
  // identify inputs by element count (all four are distinct)
  const float* h = nullptr; const int* adj = nullptr;
  const float* W = nullptr; const float* a = nullptr;
  for (int i = 0; i < n_in; ++i) {
    int s = in_sizes[i];
    if (s == NB * NN * NF) h = (const float*)d_in[i];
    else if (s == NB * NN * NN) adj = (const int*)d_in[i];
    else if (s == NF * NF) W = (const float*)d_in[i];
    else if (s == 2 * NF) a = (const float*)d_in[i];
  }

  float* out = (float*)d_out;                              // [8,2048,256] fp32
  float* att = out + (size_t)NB * NN * NF;                 // [8,2048,2048] fp32

  // ws footprint ~8.26 MB (proven safe)
  char* ws = (char*)d_ws;
  unsigned short* WhT = (unsigned short*)ws;               // 8 MB [8][256][2048] bf16
  unsigned short* WTr = (unsigned short*)(ws + 8388608);   // 128 KB [256][256] bf16
  float* u   = (float*)(ws + 8388608 + 131072);            // 1 KB
  float* v   = u + 256;                                    // 1 KB
  float* Wh1 = v + 256;                                    // 64 KB
  float* Wh2 = Wh1 + NB * NN;                              // 64 KB

  k_prep<<<257, 256, 0, stream>>>(W, a, WTr, u, v);
  k_whtp<<<NB * 128, 256, 0, stream>>>(h, WTr, u, v, WhT, Wh1, Wh2);
  k_attn<<<NB * NN / 4, 256, 0, stream>>>(adj, Wh1, Wh2, att);
  k_out<<<NB * 128, 256, 0, stream>>>(att, WhT, h, out);
}